// Round 15
// baseline (702.176 us; speedup 1.0000x reference)
//
#include <hip/hip_runtime.h>
#include <hip/hip_bf16.h>
#include <stdint.h>

// AlbertAttention forward, B=8 S=512 H=4096 NH=64 HD=64.
// quant16 skipped (grid step far below 2% absmax threshold).
// r15 GEMM: 256x256 tile, BK=32, RING-4 LDS (4 rings x {A,B} x [256][32]
// = 128 KiB), ONE single-barrier phase per K-tile: {vmcnt(8); barrier;
// 12 ds_reads; 4 gloads (tile t+3); 32 MFMA}. Counted vmcnt keeps 8 loads
// in flight; stage->use lead = 3 phases. Epilogue: r14 LDS-bounce coalesced
// stores. LN now reads bf16 xb for the residual (projb moved to qkvb).

typedef __attribute__((ext_vector_type(4))) float f32x4;
typedef __attribute__((ext_vector_type(8))) __bf16 bf16x8;

__device__ inline unsigned short f2bf(float f) {
  union { float f; unsigned u; } c; c.f = f;
  unsigned r = (c.u + 0x7fffu + ((c.u >> 16) & 1u)) >> 16;  // RNE
  return (unsigned short)r;
}

__device__ inline float bf2f(unsigned short s) {
  union { unsigned u; float f; } c; c.u = ((unsigned)s) << 16;
  return c.f;
}

__device__ inline void gload_lds16(const void* g, void* l) {
  __builtin_amdgcn_global_load_lds(
      (const __attribute__((address_space(1))) void*)g,
      (__attribute__((address_space(3))) void*)l, 16, 0, 0);
}

// ---------------- fused fp32 -> bf16 conversion (x, Wq, Wk, Wv, Wd) --------
__global__ __launch_bounds__(256) void conv_all(
    const float* __restrict__ x, const float* __restrict__ wq,
    const float* __restrict__ wk, const float* __restrict__ wv,
    const float* __restrict__ wd, unsigned short* __restrict__ out) {
  int i = blockIdx.x * 256 + threadIdx.x;  // 8-elem work item, 10485760 total
  int reg = i >> 21;
  int off = i & 2097151;
  const float* src = (reg == 0) ? x : (reg == 1) ? wq : (reg == 2) ? wk
                     : (reg == 3) ? wv : wd;
  const float4* ip = (const float4*)src;
  float4 a = ip[off * 2], b = ip[off * 2 + 1];
  union { unsigned short s[8]; uint4 v; } o;
  o.s[0] = f2bf(a.x); o.s[1] = f2bf(a.y); o.s[2] = f2bf(a.z); o.s[3] = f2bf(a.w);
  o.s[4] = f2bf(b.x); o.s[5] = f2bf(b.y); o.s[6] = f2bf(b.z); o.s[7] = f2bf(b.w);
  ((uint4*)out)[i] = o.v;
}

// ---------------- GEMM: C[M,N] = A[M,K] * B[N,K]^T + bias ------------------
// 256x256 tile, BK=32, 8 waves (2Mx4N), per-wave C = 128x64 = acc[8][4].
// LDS: 4 rings x {A,B} x [256 rows][32 cols] bf16 = 128 KiB (64-B rows).
// Swizzle: 16B granule G_phys = G_log ^ (row&3); applied on global SOURCE
// (pre-permute; global_load_lds dest linear) and on LDS reads (#21).
// Phase t (one per K-tile): VMW; BAR; rd a[8],b[4]; stg tile t+3; 32 MFMA.
// - VMW(8) certifies tile t (staged at t-3; 12 outstanding -> 8): all waves
//   pass their own vmcnt BEFORE the barrier, so after BAR every wave's
//   gloads for tile t have landed (per-wave vmcnt discipline).
// - STG at t targets ring (t+3)&3, last read at phase t-1 (>=1 barrier).
template <int BIAS_MODE>
__global__ __launch_bounds__(512, 2) void gemm_r4(
    const unsigned short* __restrict__ A, const unsigned short* __restrict__ Bw,
    const float* __restrict__ bias0, const float* __restrict__ bias1,
    const float* __restrict__ bias2, unsigned short* __restrict__ Cout,
    int M, int N, int K) {
  extern __shared__ unsigned short lds[];  // 8 regions x 8192 elems
  const int nbm = M >> 8, nbn = N >> 8, nwg = nbm * nbn;
  const int bid = blockIdx.x;
  const int wg = (bid & 7) * (nwg >> 3) + (bid >> 3);  // XCD swizzle, nwg%8==0
  const int bm = wg % nbm, bn = wg / nbm;
  const int tid = threadIdx.x, w = tid >> 6, l = tid & 63;
  const int wr = w >> 2, wc = w & 3;
  const int lr = l & 15, lg = l >> 4;
  const unsigned short* gA = A + (size_t)bm * 256 * K;
  const unsigned short* gB = Bw + (size_t)bn * 256 * K;
  const int NT = K >> 5;  // K-tiles of 32 (K=4096 -> 128)
  const int srow = tid >> 2;                       // 0..127 within row-half
  const int sg = (tid & 3) ^ (srow & 3);           // pre-swizzled src granule
  f32x4 acc[8][4] = {};
  bf16x8 a[8], b[4];

// stage one BK=32 tile operand (256 rows x 32 cols) = 2 gloads/thread
#define STG(op, ring, kt)                                                      \
  {                                                                            \
    const unsigned short* g_ = (op) ? gB : gA;                                 \
    _Pragma("unroll")                                                          \
    for (int j_ = 0; j_ < 2; ++j_) {                                           \
      gload_lds16(g_ + (size_t)(j_ * 128 + srow) * K + (kt) * 32 + sg * 8,     \
                  &lds[((ring) * 2 + (op)) * 8192 + j_ * 4096 + w * 512]);     \
    }                                                                          \
  }

#define RDA(ring, m)                                                           \
  (*(const bf16x8*)&lds[((ring) * 2 + 0) * 8192 +                              \
                        (wr * 128 + (m) * 16 + lr) * 32 +                      \
                        ((lg ^ (lr & 3)) << 3)])
#define RDB(ring, n)                                                           \
  (*(const bf16x8*)&lds[((ring) * 2 + 1) * 8192 +                              \
                        (wc * 64 + (n) * 16 + lr) * 32 +                       \
                        ((lg ^ (lr & 3)) << 3)])

#define BAR() __builtin_amdgcn_s_barrier()
#define VMW8() asm volatile("s_waitcnt vmcnt(8)" ::: "memory")
#define VMW4() asm volatile("s_waitcnt vmcnt(4)" ::: "memory")
#define VMW0() asm volatile("s_waitcnt vmcnt(0)" ::: "memory")

  // prologue: stage tiles 0,1,2 (12 gloads/thread outstanding)
  STG(0, 0, 0); STG(1, 0, 0);
  STG(0, 1, 1); STG(1, 1, 1);
  STG(0, 2, 2); STG(1, 2, 2);

  for (int t = 0; t < NT; ++t) {
    if (t + 2 < NT) VMW8();
    else if (t + 1 < NT) VMW4();
    else VMW0();
    BAR();
    const int ring = t & 3;
#pragma unroll
    for (int m_ = 0; m_ < 8; ++m_) a[m_] = RDA(ring, m_);
#pragma unroll
    for (int n_ = 0; n_ < 4; ++n_) b[n_] = RDB(ring, n_);
    if (t + 3 < NT) {
      const int pring = (t + 3) & 3;
      STG(0, pring, t + 3); STG(1, pring, t + 3);
    }
    __builtin_amdgcn_s_setprio(1);
#pragma unroll
    for (int m_ = 0; m_ < 8; ++m_)
#pragma unroll
      for (int n_ = 0; n_ < 4; ++n_)
        acc[m_][n_] = __builtin_amdgcn_mfma_f32_16x16x32_bf16(
            a[m_], b[n_], acc[m_][n_], 0, 0, 0);
    __builtin_amdgcn_s_setprio(0);
  }

  // ---- coalesced epilogue: per-wave [128][64] bf16 bounce tile ----
  __syncthreads();  // all LDS traffic drained; rings dead
  unsigned short* Cb = lds + w * 8192;  // 16 KiB per wave
#pragma unroll
  for (int n = 0; n < 4; ++n) {
    int col = bn * 256 + wc * 64 + n * 16 + lr;
    float bv = 0.f;
    if (BIAS_MODE == 1) bv = bias0[col];
    else if (BIAS_MODE == 2)
      bv = (col < 4096) ? bias0[col] : (col < 8192 ? bias1[col - 4096] : bias2[col - 8192]);
#pragma unroll
    for (int m = 0; m < 8; ++m)
#pragma unroll
      for (int r = 0; r < 4; ++r) {
        int row = m * 16 + lg * 4 + r;  // 0..127
        int c2 = n * 16 + lr;           // 0..63
        Cb[row * 64 + (c2 ^ ((row & 7) << 3))] = f2bf(acc[m][n][r] + bv);
      }
  }
#pragma unroll
  for (int j = 0; j < 16; ++j) {
    int i16 = j * 64 + l;   // granule index 0..1023
    int row = i16 >> 3;     // 0..127
    int g = i16 & 7;
    uint4 v = *(const uint4*)&Cb[row * 64 + ((g * 8) ^ ((row & 7) << 3))];
    int grow = bm * 256 + wr * 128 + row;
    int gcol = bn * 256 + wc * 64 + g * 8;
    *(uint4*)&Cout[(size_t)grow * N + gcol] = v;
  }
#undef STG
#undef RDA
#undef RDB
#undef BAR
#undef VMW8
#undef VMW4
#undef VMW0
}

// ---------------- attention: one block per (b,h) head ----------------
__global__ __launch_bounds__(512) void attn_kernel(
    const unsigned short* __restrict__ qkv, const float* __restrict__ mask,
    unsigned short* __restrict__ ctx) {
  extern __shared__ char smem[];
  unsigned short* Kt = (unsigned short*)smem;   // 512*64 elems (64 KiB)
  unsigned short* Vt = Kt + 512 * 64;           // 64*512 elems (64 KiB)
  unsigned short* Pb = Vt + 64 * 512;           // 8 * 16*64 elems (16 KiB)
  float* Mb = (float*)(Pb + 8 * 16 * 64);       // 512 floats (2 KiB)

  const int bid = blockIdx.x;
  const int b = bid >> 6, h = bid & 63;
  const int tid = threadIdx.x, w = tid >> 6, l = tid & 63;
  const size_t tokbase = (size_t)b * 512;

  Mb[tid < 512 ? tid : 0] = mask[b * 512 + (tid < 512 ? tid : 0)];
#pragma unroll
  for (int it = 0; it < 8; ++it) {
    int idx = it * 512 + tid;
    int row = idx >> 3, g = (idx & 7) << 3;
    const unsigned short* src = qkv + (tokbase + row) * 12288 + 4096 + h * 64 + g;
    uint4 v = *(const uint4*)src;
    *(uint4*)&Kt[row * 64 + (g ^ ((row & 7) << 3))] = v;
  }
#pragma unroll
  for (int it = 0; it < 8; ++it) {
    int idx = it * 512 + tid;
    int key = idx >> 3, g = (idx & 7) << 3;
    const unsigned short* src = qkv + (tokbase + key) * 12288 + 8192 + h * 64 + g;
    uint4 v = *(const uint4*)src;
    const unsigned short* e = (const unsigned short*)&v;
#pragma unroll
    for (int i = 0; i < 8; i++) {
      int d = g + i;
      Vt[d * 512 + (key ^ ((d & 7) << 3))] = e[i];
    }
  }
  __syncthreads();

  unsigned short* Pw = Pb + w * 16 * 64;
  const int lr = l & 15, lg = l >> 4;

  for (int c = 0; c < 4; ++c) {
    int q0 = w * 64 + c * 16;
    const unsigned short* qsrc = qkv + (tokbase + q0 + lr) * 12288 + h * 64 + lg * 8;
    bf16x8 qa0 = *(const bf16x8*)qsrc;
    bf16x8 qa1 = *(const bf16x8*)(qsrc + 32);
    f32x4 sc[32];
    f32x4 zero = {0.f, 0.f, 0.f, 0.f};
    __builtin_amdgcn_s_setprio(1);
#pragma unroll
    for (int n = 0; n < 32; n++) {
      int key = n * 16 + lr;
      bf16x8 kb0 = *(const bf16x8*)&Kt[key * 64 + ((lg * 8) ^ ((key & 7) << 3))];
      bf16x8 kb1 = *(const bf16x8*)&Kt[key * 64 + ((32 + lg * 8) ^ ((key & 7) << 3))];
      f32x4 a = __builtin_amdgcn_mfma_f32_16x16x32_bf16(qa0, kb0, zero, 0, 0, 0);
      sc[n] = __builtin_amdgcn_mfma_f32_16x16x32_bf16(qa1, kb1, a, 0, 0, 0);
    }
    __builtin_amdgcn_s_setprio(0);
    float rmax[4] = {-1e30f, -1e30f, -1e30f, -1e30f};
#pragma unroll
    for (int n = 0; n < 32; n++) {
      float mk = Mb[n * 16 + lr];
#pragma unroll
      for (int r = 0; r < 4; r++) {
        float s = sc[n][r] * 0.125f + mk;
        sc[n][r] = s;
        rmax[r] = fmaxf(rmax[r], s);
      }
    }
#pragma unroll
    for (int r = 0; r < 4; r++) {
      float m = rmax[r];
      m = fmaxf(m, __shfl_xor(m, 8)); m = fmaxf(m, __shfl_xor(m, 4));
      m = fmaxf(m, __shfl_xor(m, 2)); m = fmaxf(m, __shfl_xor(m, 1));
      rmax[r] = m;
    }
    float rsum[4] = {0.f, 0.f, 0.f, 0.f};
#pragma unroll
    for (int n = 0; n < 32; n++)
#pragma unroll
      for (int r = 0; r < 4; r++) {
        float p = __expf(sc[n][r] - rmax[r]);
        sc[n][r] = p;
        rsum[r] += p;
      }
#pragma unroll
    for (int r = 0; r < 4; r++) {
      float s = rsum[r];
      s += __shfl_xor(s, 8); s += __shfl_xor(s, 4);
      s += __shfl_xor(s, 2); s += __shfl_xor(s, 1);
      rsum[r] = s;
    }
    f32x4 cacc[4] = {};
#pragma unroll
    for (int kb = 0; kb < 8; ++kb) {
#pragma unroll
      for (int nn = 0; nn < 4; ++nn) {
        int colp = nn * 16 + lr;
#pragma unroll
        for (int r = 0; r < 4; r++) {
          int m = lg * 4 + r;
          Pw[m * 64 + (colp ^ ((m & 7) << 3))] = f2bf(sc[kb * 4 + nn][r]);
        }
      }
      bf16x8 pa0 = *(const bf16x8*)&Pw[lr * 64 + ((lg * 8) ^ ((lr & 7) << 3))];
      bf16x8 pa1 = *(const bf16x8*)&Pw[lr * 64 + ((32 + lg * 8) ^ ((lr & 7) << 3))];
      __builtin_amdgcn_s_setprio(1);
#pragma unroll
      for (int dt = 0; dt < 4; ++dt) {
        int vr = dt * 16 + lr;
        int k0 = kb * 64 + lg * 8;
        bf16x8 vb0 = *(const bf16x8*)&Vt[vr * 512 + (k0 ^ ((vr & 7) << 3))];
        bf16x8 vb1 = *(const bf16x8*)&Vt[vr * 512 + ((k0 + 32) ^ ((vr & 7) << 3))];
        cacc[dt] = __builtin_amdgcn_mfma_f32_16x16x32_bf16(pa0, vb0, cacc[dt], 0, 0, 0);
        cacc[dt] = __builtin_amdgcn_mfma_f32_16x16x32_bf16(pa1, vb1, cacc[dt], 0, 0, 0);
      }
      __builtin_amdgcn_s_setprio(0);
    }
    // coalesced ctx write: bounce [16 q][64 d] through Pw, then uint4 stores
#pragma unroll
    for (int dt = 0; dt < 4; ++dt)
#pragma unroll
      for (int r = 0; r < 4; r++) {
        int m = lg * 4 + r;
        int c2 = dt * 16 + lr;
        Pw[m * 64 + (c2 ^ ((m & 7) << 3))] = f2bf(cacc[dt][r] / rsum[r]);
      }
#pragma unroll
    for (int j = 0; j < 2; ++j) {
      int i16 = j * 64 + l;  // granule 0..127
      int row = i16 >> 3;    // 0..15
      int g = i16 & 7;
      uint4 v = *(const uint4*)&Pw[row * 64 + ((g * 8) ^ ((row & 7) << 3))];
      *(uint4*)&ctx[(tokbase + q0 + row) * 4096 + h * 64 + g * 8] = v;
    }
  }
}

// -------- residual + LayerNorm: out = LN(xb_bf16 + proj_bf16) -------------
__global__ __launch_bounds__(256) void ln_kernel(
    const unsigned short* __restrict__ xb, const unsigned short* __restrict__ proj,
    float* __restrict__ out,
    const float* __restrict__ lnw, const float* __restrict__ lnb) {
  int t = blockIdx.x;
  const uint4* xr = (const uint4*)(xb + (size_t)t * 4096);
  const uint4* pr = (const uint4*)(proj + (size_t)t * 4096);
  float y[16];
  float sum = 0.f, sq = 0.f;
#pragma unroll
  for (int j = 0; j < 2; j++) {
    int i8 = j * 256 + threadIdx.x;  // 8-elem granule 0..511
    uint4 xv = xr[i8];
    uint4 pv = pr[i8];
    const unsigned short* xs = (const unsigned short*)&xv;
    const unsigned short* ps = (const unsigned short*)&pv;
#pragma unroll
    for (int e = 0; e < 8; ++e) {
      float yy = bf2f(xs[e]) + bf2f(ps[e]);
      y[j * 8 + e] = yy;
      sum += yy;
      sq += yy * yy;
    }
  }
#pragma unroll
  for (int off = 32; off >= 1; off >>= 1) {
    sum += __shfl_down(sum, off);
    sq += __shfl_down(sq, off);
  }
  __shared__ float red[8];
  int w = threadIdx.x >> 6, l = threadIdx.x & 63;
  if (l == 0) { red[w] = sum; red[4 + w] = sq; }
  __syncthreads();
  float ts = red[0] + red[1] + red[2] + red[3];
  float tq = red[4] + red[5] + red[6] + red[7];
  float mean = ts * (1.f / 4096.f);
  float var = tq * (1.f / 4096.f) - mean * mean;
  float rs = rsqrtf(var + 1e-12f);
  float4* orow = (float4*)(out + (size_t)t * 4096);
#pragma unroll
  for (int j = 0; j < 2; j++) {
    int i8 = j * 256 + threadIdx.x;
#pragma unroll
    for (int hh = 0; hh < 2; ++hh) {
      int i4 = i8 * 2 + hh;
      float4 wv = ((const float4*)lnw)[i4];
      float4 bb = ((const float4*)lnb)[i4];
      float4 o;
      o.x = (y[j * 8 + hh * 4 + 0] - mean) * rs * wv.x + bb.x;
      o.y = (y[j * 8 + hh * 4 + 1] - mean) * rs * wv.y + bb.y;
      o.z = (y[j * 8 + hh * 4 + 2] - mean) * rs * wv.z + bb.z;
      o.w = (y[j * 8 + hh * 4 + 3] - mean) * rs * wv.w + bb.w;
      orow[i4] = o;
    }
  }
}

extern "C" void kernel_launch(void* const* d_in, const int* in_sizes, int n_in,
                              void* d_out, int out_size, void* d_ws, size_t ws_size,
                              hipStream_t stream) {
  const float* x   = (const float*)d_in[0];
  const float* msk = (const float*)d_in[1];
  const float* Wq  = (const float*)d_in[2];
  const float* bq  = (const float*)d_in[3];
  const float* Wk  = (const float*)d_in[4];
  const float* bk  = (const float*)d_in[5];
  const float* Wv  = (const float*)d_in[6];
  const float* bv  = (const float*)d_in[7];
  const float* Wd  = (const float*)d_in[8];
  const float* bd  = (const float*)d_in[9];
  const float* lnw = (const float*)d_in[10];
  const float* lnb = (const float*)d_in[11];
  float* out = (float*)d_out;

  // workspace layout (bf16 elems), 256 MiB total:
  unsigned short* xb    = (unsigned short*)d_ws;            // 16M
  unsigned short* wqkvb = xb + (size_t)16777216;            // 48M
  unsigned short* wdb   = wqkvb + (size_t)50331648;         // 16M
  unsigned short* qkvb  = wdb + (size_t)16777216;           // 48M
  unsigned short* ctxb  = wqkvb;  // alias: W_qkv dead after GEMM1
  unsigned short* projb = qkvb;   // alias: q/k/v dead after attn (xb stays!)

  // fused conversions: 5 tensors x 2M 8-elem items
  conv_all<<<40960, 256, 0, stream>>>(x, Wq, Wk, Wv, Wd, xb);

  (void)hipFuncSetAttribute((const void*)(gemm_r4<2>),
                            hipFuncAttributeMaxDynamicSharedMemorySize, 131072);
  (void)hipFuncSetAttribute((const void*)(gemm_r4<1>),
                            hipFuncAttributeMaxDynamicSharedMemorySize, 131072);

  // QKV: [4096,12288] = xb[4096,4096] * Wqkv[12288,4096]^T + b  (nwg=768)
  gemm_r4<2><<<768, 512, 131072, stream>>>(xb, wqkvb, bq, bk, bv, qkvb,
                                           4096, 12288, 4096);

  // attention: 512 heads
  (void)hipFuncSetAttribute((const void*)attn_kernel,
                            hipFuncAttributeMaxDynamicSharedMemorySize, 149504);
  attn_kernel<<<512, 512, 149504, stream>>>(qkvb, msk, ctxb);

  // proj (bf16): projb = ctx[4096,4096] * Wd[4096,4096]^T + bd  (nwg=256)
  gemm_r4<1><<<256, 512, 131072, stream>>>(ctxb, wdb, bd, nullptr, nullptr,
                                           projb, 4096, 4096, 4096);

  // residual + LN: out = LN(xb + projb)  (both bf16)
  ln_kernel<<<4096, 256, 0, stream>>>(xb, projb, out, lnw, lnb);
}

// Round 16
// 638.858 us; speedup vs baseline: 1.0991x; 1.0991x over previous
//
#include <hip/hip_runtime.h>
#include <hip/hip_bf16.h>
#include <stdint.h>

// AlbertAttention forward, B=8 S=512 H=4096 NH=64 HD=64.
// quant16 skipped (grid step far below 2% absmax threshold).
// r16 = r14 GEMM champion (256x256 tile, BK=64, 8 waves, single-barrier
// 4-phase, 3-bit XOR swizzle both-sides -> 0 bank conflicts, LDS-bounce
// coalesced epilogue) + r15 tail (LN reads bf16 xb residual; projb aliases
// qkvb). BK=32 ring variants are structurally bank-conflicted (r3/r15).

typedef __attribute__((ext_vector_type(4))) float f32x4;
typedef __attribute__((ext_vector_type(8))) __bf16 bf16x8;

__device__ inline unsigned short f2bf(float f) {
  union { float f; unsigned u; } c; c.f = f;
  unsigned r = (c.u + 0x7fffu + ((c.u >> 16) & 1u)) >> 16;  // RNE
  return (unsigned short)r;
}

__device__ inline float bf2f(unsigned short s) {
  union { unsigned u; float f; } c; c.u = ((unsigned)s) << 16;
  return c.f;
}

__device__ inline void gload_lds16(const void* g, void* l) {
  __builtin_amdgcn_global_load_lds(
      (const __attribute__((address_space(1))) void*)g,
      (__attribute__((address_space(3))) void*)l, 16, 0, 0);
}

// ---------------- fused fp32 -> bf16 conversion (x, Wq, Wk, Wv, Wd) --------
__global__ __launch_bounds__(256) void conv_all(
    const float* __restrict__ x, const float* __restrict__ wq,
    const float* __restrict__ wk, const float* __restrict__ wv,
    const float* __restrict__ wd, unsigned short* __restrict__ out) {
  int i = blockIdx.x * 256 + threadIdx.x;  // 8-elem work item, 10485760 total
  int reg = i >> 21;
  int off = i & 2097151;
  const float* src = (reg == 0) ? x : (reg == 1) ? wq : (reg == 2) ? wk
                     : (reg == 3) ? wv : wd;
  const float4* ip = (const float4*)src;
  float4 a = ip[off * 2], b = ip[off * 2 + 1];
  union { unsigned short s[8]; uint4 v; } o;
  o.s[0] = f2bf(a.x); o.s[1] = f2bf(a.y); o.s[2] = f2bf(a.z); o.s[3] = f2bf(a.w);
  o.s[4] = f2bf(b.x); o.s[5] = f2bf(b.y); o.s[6] = f2bf(b.z); o.s[7] = f2bf(b.w);
  ((uint4*)out)[i] = o.v;
}

// ---------------- GEMM: C[M,N] = A[M,K] * B[N,K]^T + bias ------------------
// 256x256 tile, BK=64, 8 waves (2Mx4N), per-wave C = 128x64 = acc[8][4].
// LDS: {A,B} x {buf0,buf1} x [256 rows][64 cols] bf16 = 128 KiB, 128-B rows.
// Swizzle: 16B granule G_phys = G_log ^ (row&7); applied on global SOURCE
// (pre-permute; global_load_lds dest stays linear) and on LDS reads (#21).
// Single-barrier phases, 4 per K-tile pair (T0=2i in buf0, T1=2i+1 in buf1):
//   P0: rd A(buf0,mh0)+B(buf0);  stg A0,A1(T1->buf1);            BAR; 32 MFMA
//   P1: rd A(buf0,mh1);          stg B0,B1(T2->buf0); vmcnt(4);  BAR; 32 MFMA
//   P2: rd A(buf1,mh0)+B(buf1);  stg A0,A1(T2->buf0);            BAR; 32 MFMA
//   P3: rd A(buf1,mh1);          stg B0,B1(T3->buf1); vmcnt(4);  BAR; 32 MFMA
// Epilogue: per-wave 16 KiB LDS bounce (XOR-swz, <=2-way) -> uint4 stores.
template <int BIAS_MODE>
__global__ __launch_bounds__(512, 2) void gemm_4p(
    const unsigned short* __restrict__ A, const unsigned short* __restrict__ Bw,
    const float* __restrict__ bias0, const float* __restrict__ bias1,
    const float* __restrict__ bias2, unsigned short* __restrict__ Cout,
    int M, int N, int K) {
  extern __shared__ unsigned short lds[];  // 4 regions x 16384 elems
  const int nbm = M >> 8, nbn = N >> 8, nwg = nbm * nbn;
  const int bid = blockIdx.x;
  const int wg = (bid & 7) * (nwg >> 3) + (bid >> 3);  // XCD swizzle, nwg%8==0
  const int bm = wg % nbm, bn = wg / nbm;
  const int tid = threadIdx.x, w = tid >> 6, l = tid & 63;
  const int wr = w >> 2, wc = w & 3;
  const int lr = l & 15, lg = l >> 4;
  const unsigned short* gA = A + (size_t)bm * 256 * K;
  const unsigned short* gB = Bw + (size_t)bn * 256 * K;
  const int NT = K >> 6;  // K-tiles (K=4096 -> 64; even)
  const int srow = tid >> 3;                      // 0..63 within 64-row chunk
  const int scol = ((tid & 7) ^ (srow & 7)) << 3; // pre-swizzled source granule
  f32x4 acc[8][4] = {};
  bf16x8 a[8], b[8];

#define STG(op, buf, h, kt)                                                    \
  {                                                                            \
    const unsigned short* g_ = (op) ? gB : gA;                                 \
    _Pragma("unroll")                                                          \
    for (int j_ = 0; j_ < 2; ++j_) {                                           \
      gload_lds16(                                                             \
          g_ + (size_t)((h) * 128 + j_ * 64 + srow) * K + (kt) * 64 + scol,    \
          &lds[((op) * 2 + (buf)) * 16384 + ((h) * 128 + j_ * 64) * 64 +       \
               w * 512]);                                                      \
    }                                                                          \
  }

#define RDA(buf, m, kk)                                                        \
  (*(const bf16x8*)&lds[(buf) * 16384 + (wr * 128 + (m) * 16 + lr) * 64 +      \
                        ((((kk) * 4 + lg) ^ (lr & 7)) << 3)])
#define RDB(buf, n, kk)                                                        \
  (*(const bf16x8*)&lds[(2 + (buf)) * 16384 + (wc * 64 + (n) * 16 + lr) * 64 + \
                        ((((kk) * 4 + lg) ^ (lr & 7)) << 3)])

#define LDA(buf, mh)                                                           \
  _Pragma("unroll")                                                            \
  for (int m_ = 0; m_ < 4; ++m_) {                                             \
    a[m_ * 2 + 0] = RDA(buf, (mh) * 4 + m_, 0);                                \
    a[m_ * 2 + 1] = RDA(buf, (mh) * 4 + m_, 1);                                \
  }
#define LDB(buf, nh)                                                           \
  _Pragma("unroll")                                                            \
  for (int n_ = 0; n_ < 2; ++n_) {                                             \
    b[((nh) * 2 + n_) * 2 + 0] = RDB(buf, (nh) * 2 + n_, 0);                   \
    b[((nh) * 2 + n_) * 2 + 1] = RDB(buf, (nh) * 2 + n_, 1);                   \
  }

#define MM(mbase, nbase)                                                       \
  __builtin_amdgcn_s_setprio(1);                                               \
  _Pragma("unroll")                                                            \
  for (int m_ = 0; m_ < 4; ++m_) {                                             \
    _Pragma("unroll")                                                          \
    for (int n_ = 0; n_ < 2; ++n_) {                                           \
      acc[(mbase) + m_][(nbase) + n_] =                                        \
          __builtin_amdgcn_mfma_f32_16x16x32_bf16(                             \
              a[m_ * 2], b[((nbase) + n_) * 2], acc[(mbase) + m_][(nbase) + n_],\
              0, 0, 0);                                                        \
      acc[(mbase) + m_][(nbase) + n_] =                                        \
          __builtin_amdgcn_mfma_f32_16x16x32_bf16(                             \
              a[m_ * 2 + 1], b[((nbase) + n_) * 2 + 1],                        \
              acc[(mbase) + m_][(nbase) + n_], 0, 0, 0);                       \
    }                                                                          \
  }                                                                            \
  __builtin_amdgcn_s_setprio(0);

#define BAR() __builtin_amdgcn_s_barrier()
#define VMW4() asm volatile("s_waitcnt vmcnt(4)" ::: "memory")
#define VMW0() asm volatile("s_waitcnt vmcnt(0)" ::: "memory")

  // prologue: T0 all 4 halves + B0,B1(T1); vmcnt(4) certifies T0
  STG(0, 0, 0, 0); STG(0, 0, 1, 0); STG(1, 0, 0, 0); STG(1, 0, 1, 0);
  STG(1, 1, 0, 1); STG(1, 1, 1, 1);
  VMW4();
  BAR();

  const int NI = NT >> 1;
  for (int i = 0; i < NI; ++i) {
    const int t1 = 2 * i + 1, t2 = 2 * i + 2, t3 = 2 * i + 3;
    const bool s2 = t2 < NT, s3 = t3 < NT;
    // ---- P0: rd T0 mh0+B; stage A0,A1(T1 -> buf1)
    LDA(0, 0); LDB(0, 0); LDB(0, 1);
    STG(0, 1, 0, t1); STG(0, 1, 1, t1);
    BAR();
    MM(0, 0); MM(0, 2);
    // ---- P1: rd T0 mh1; stage B0,B1(T2 -> buf0); certify T1
    LDA(0, 1);
    if (s2) { STG(1, 0, 0, t2); STG(1, 0, 1, t2); VMW4(); } else VMW0();
    BAR();
    MM(4, 0); MM(4, 2);
    // ---- P2: rd T1 mh0+B; stage A0,A1(T2 -> buf0)
    LDA(1, 0); LDB(1, 0); LDB(1, 1);
    if (s2) { STG(0, 0, 0, t2); STG(0, 0, 1, t2); }
    BAR();
    MM(0, 0); MM(0, 2);
    // ---- P3: rd T1 mh1; stage B0,B1(T3 -> buf1); certify T2
    LDA(1, 1);
    if (s3) { STG(1, 1, 0, t3); STG(1, 1, 1, t3); VMW4(); }
    else if (s2) VMW0();
    BAR();
    MM(4, 0); MM(4, 2);
  }

  // ---- coalesced epilogue: per-wave [128][64] bf16 bounce tile ----
  __syncthreads();  // full drain: K-loop LDS traffic finished everywhere
  unsigned short* Cb = lds + w * 8192;  // 16 KiB per wave
#pragma unroll
  for (int n = 0; n < 4; ++n) {
    int col = bn * 256 + wc * 64 + n * 16 + lr;
    float bv = 0.f;
    if (BIAS_MODE == 1) bv = bias0[col];
    else if (BIAS_MODE == 2)
      bv = (col < 4096) ? bias0[col] : (col < 8192 ? bias1[col - 4096] : bias2[col - 8192]);
#pragma unroll
    for (int m = 0; m < 8; ++m)
#pragma unroll
      for (int r = 0; r < 4; ++r) {
        int row = m * 16 + lg * 4 + r;  // 0..127
        int c2 = n * 16 + lr;           // 0..63
        Cb[row * 64 + (c2 ^ ((row & 7) << 3))] = f2bf(acc[m][n][r] + bv);
      }
  }
#pragma unroll
  for (int j = 0; j < 16; ++j) {
    int i16 = j * 64 + l;   // granule index 0..1023
    int row = i16 >> 3;     // 0..127
    int g = i16 & 7;
    uint4 v = *(const uint4*)&Cb[row * 64 + ((g * 8) ^ ((row & 7) << 3))];
    int grow = bm * 256 + wr * 128 + row;
    int gcol = bn * 256 + wc * 64 + g * 8;
    *(uint4*)&Cout[(size_t)grow * N + gcol] = v;
  }
#undef STG
#undef RDA
#undef RDB
#undef LDA
#undef LDB
#undef MM
#undef BAR
#undef VMW4
#undef VMW0
}

// ---------------- attention: one block per (b,h) head ----------------
__global__ __launch_bounds__(512) void attn_kernel(
    const unsigned short* __restrict__ qkv, const float* __restrict__ mask,
    unsigned short* __restrict__ ctx) {
  extern __shared__ char smem[];
  unsigned short* Kt = (unsigned short*)smem;   // 512*64 elems (64 KiB)
  unsigned short* Vt = Kt + 512 * 64;           // 64*512 elems (64 KiB)
  unsigned short* Pb = Vt + 64 * 512;           // 8 * 16*64 elems (16 KiB)
  float* Mb = (float*)(Pb + 8 * 16 * 64);       // 512 floats (2 KiB)

  const int bid = blockIdx.x;
  const int b = bid >> 6, h = bid & 63;
  const int tid = threadIdx.x, w = tid >> 6, l = tid & 63;
  const size_t tokbase = (size_t)b * 512;

  Mb[tid < 512 ? tid : 0] = mask[b * 512 + (tid < 512 ? tid : 0)];
#pragma unroll
  for (int it = 0; it < 8; ++it) {
    int idx = it * 512 + tid;
    int row = idx >> 3, g = (idx & 7) << 3;
    const unsigned short* src = qkv + (tokbase + row) * 12288 + 4096 + h * 64 + g;
    uint4 v = *(const uint4*)src;
    *(uint4*)&Kt[row * 64 + (g ^ ((row & 7) << 3))] = v;
  }
#pragma unroll
  for (int it = 0; it < 8; ++it) {
    int idx = it * 512 + tid;
    int key = idx >> 3, g = (idx & 7) << 3;
    const unsigned short* src = qkv + (tokbase + key) * 12288 + 8192 + h * 64 + g;
    uint4 v = *(const uint4*)src;
    const unsigned short* e = (const unsigned short*)&v;
#pragma unroll
    for (int i = 0; i < 8; i++) {
      int d = g + i;
      Vt[d * 512 + (key ^ ((d & 7) << 3))] = e[i];
    }
  }
  __syncthreads();

  unsigned short* Pw = Pb + w * 16 * 64;
  const int lr = l & 15, lg = l >> 4;

  for (int c = 0; c < 4; ++c) {
    int q0 = w * 64 + c * 16;
    const unsigned short* qsrc = qkv + (tokbase + q0 + lr) * 12288 + h * 64 + lg * 8;
    bf16x8 qa0 = *(const bf16x8*)qsrc;
    bf16x8 qa1 = *(const bf16x8*)(qsrc + 32);
    f32x4 sc[32];
    f32x4 zero = {0.f, 0.f, 0.f, 0.f};
    __builtin_amdgcn_s_setprio(1);
#pragma unroll
    for (int n = 0; n < 32; n++) {
      int key = n * 16 + lr;
      bf16x8 kb0 = *(const bf16x8*)&Kt[key * 64 + ((lg * 8) ^ ((key & 7) << 3))];
      bf16x8 kb1 = *(const bf16x8*)&Kt[key * 64 + ((32 + lg * 8) ^ ((key & 7) << 3))];
      f32x4 a = __builtin_amdgcn_mfma_f32_16x16x32_bf16(qa0, kb0, zero, 0, 0, 0);
      sc[n] = __builtin_amdgcn_mfma_f32_16x16x32_bf16(qa1, kb1, a, 0, 0, 0);
    }
    __builtin_amdgcn_s_setprio(0);
    float rmax[4] = {-1e30f, -1e30f, -1e30f, -1e30f};
#pragma unroll
    for (int n = 0; n < 32; n++) {
      float mk = Mb[n * 16 + lr];
#pragma unroll
      for (int r = 0; r < 4; r++) {
        float s = sc[n][r] * 0.125f + mk;
        sc[n][r] = s;
        rmax[r] = fmaxf(rmax[r], s);
      }
    }
#pragma unroll
    for (int r = 0; r < 4; r++) {
      float m = rmax[r];
      m = fmaxf(m, __shfl_xor(m, 8)); m = fmaxf(m, __shfl_xor(m, 4));
      m = fmaxf(m, __shfl_xor(m, 2)); m = fmaxf(m, __shfl_xor(m, 1));
      rmax[r] = m;
    }
    float rsum[4] = {0.f, 0.f, 0.f, 0.f};
#pragma unroll
    for (int n = 0; n < 32; n++)
#pragma unroll
      for (int r = 0; r < 4; r++) {
        float p = __expf(sc[n][r] - rmax[r]);
        sc[n][r] = p;
        rsum[r] += p;
      }
#pragma unroll
    for (int r = 0; r < 4; r++) {
      float s = rsum[r];
      s += __shfl_xor(s, 8); s += __shfl_xor(s, 4);
      s += __shfl_xor(s, 2); s += __shfl_xor(s, 1);
      rsum[r] = s;
    }
    f32x4 cacc[4] = {};
#pragma unroll
    for (int kb = 0; kb < 8; ++kb) {
#pragma unroll
      for (int nn = 0; nn < 4; ++nn) {
        int colp = nn * 16 + lr;
#pragma unroll
        for (int r = 0; r < 4; r++) {
          int m = lg * 4 + r;
          Pw[m * 64 + (colp ^ ((m & 7) << 3))] = f2bf(sc[kb * 4 + nn][r]);
        }
      }
      bf16x8 pa0 = *(const bf16x8*)&Pw[lr * 64 + ((lg * 8) ^ ((lr & 7) << 3))];
      bf16x8 pa1 = *(const bf16x8*)&Pw[lr * 64 + ((32 + lg * 8) ^ ((lr & 7) << 3))];
      __builtin_amdgcn_s_setprio(1);
#pragma unroll
      for (int dt = 0; dt < 4; ++dt) {
        int vr = dt * 16 + lr;
        int k0 = kb * 64 + lg * 8;
        bf16x8 vb0 = *(const bf16x8*)&Vt[vr * 512 + (k0 ^ ((vr & 7) << 3))];
        bf16x8 vb1 = *(const bf16x8*)&Vt[vr * 512 + ((k0 + 32) ^ ((vr & 7) << 3))];
        cacc[dt] = __builtin_amdgcn_mfma_f32_16x16x32_bf16(pa0, vb0, cacc[dt], 0, 0, 0);
        cacc[dt] = __builtin_amdgcn_mfma_f32_16x16x32_bf16(pa1, vb1, cacc[dt], 0, 0, 0);
      }
      __builtin_amdgcn_s_setprio(0);
    }
    // coalesced ctx write: bounce [16 q][64 d] through Pw, then uint4 stores
#pragma unroll
    for (int dt = 0; dt < 4; ++dt)
#pragma unroll
      for (int r = 0; r < 4; r++) {
        int m = lg * 4 + r;
        int c2 = dt * 16 + lr;
        Pw[m * 64 + (c2 ^ ((m & 7) << 3))] = f2bf(cacc[dt][r] / rsum[r]);
      }
#pragma unroll
    for (int j = 0; j < 2; ++j) {
      int i16 = j * 64 + l;  // granule 0..127
      int row = i16 >> 3;    // 0..15
      int g = i16 & 7;
      uint4 v = *(const uint4*)&Pw[row * 64 + ((g * 8) ^ ((row & 7) << 3))];
      *(uint4*)&ctx[(tokbase + q0 + row) * 4096 + h * 64 + g * 8] = v;
    }
  }
}

// -------- residual + LayerNorm: out = LN(xb_bf16 + proj_bf16) -------------
__global__ __launch_bounds__(256) void ln_kernel(
    const unsigned short* __restrict__ xb, const unsigned short* __restrict__ proj,
    float* __restrict__ out,
    const float* __restrict__ lnw, const float* __restrict__ lnb) {
  int t = blockIdx.x;
  const uint4* xr = (const uint4*)(xb + (size_t)t * 4096);
  const uint4* pr = (const uint4*)(proj + (size_t)t * 4096);
  float y[16];
  float sum = 0.f, sq = 0.f;
#pragma unroll
  for (int j = 0; j < 2; j++) {
    int i8 = j * 256 + threadIdx.x;  // 8-elem granule 0..511
    uint4 xv = xr[i8];
    uint4 pv = pr[i8];
    const unsigned short* xs = (const unsigned short*)&xv;
    const unsigned short* ps = (const unsigned short*)&pv;
#pragma unroll
    for (int e = 0; e < 8; ++e) {
      float yy = bf2f(xs[e]) + bf2f(ps[e]);
      y[j * 8 + e] = yy;
      sum += yy;
      sq += yy * yy;
    }
  }
#pragma unroll
  for (int off = 32; off >= 1; off >>= 1) {
    sum += __shfl_down(sum, off);
    sq += __shfl_down(sq, off);
  }
  __shared__ float red[8];
  int w = threadIdx.x >> 6, l = threadIdx.x & 63;
  if (l == 0) { red[w] = sum; red[4 + w] = sq; }
  __syncthreads();
  float ts = red[0] + red[1] + red[2] + red[3];
  float tq = red[4] + red[5] + red[6] + red[7];
  float mean = ts * (1.f / 4096.f);
  float var = tq * (1.f / 4096.f) - mean * mean;
  float rs = rsqrtf(var + 1e-12f);
  float4* orow = (float4*)(out + (size_t)t * 4096);
#pragma unroll
  for (int j = 0; j < 2; j++) {
    int i8 = j * 256 + threadIdx.x;
#pragma unroll
    for (int hh = 0; hh < 2; ++hh) {
      int i4 = i8 * 2 + hh;
      float4 wv = ((const float4*)lnw)[i4];
      float4 bb = ((const float4*)lnb)[i4];
      float4 o;
      o.x = (y[j * 8 + hh * 4 + 0] - mean) * rs * wv.x + bb.x;
      o.y = (y[j * 8 + hh * 4 + 1] - mean) * rs * wv.y + bb.y;
      o.z = (y[j * 8 + hh * 4 + 2] - mean) * rs * wv.z + bb.z;
      o.w = (y[j * 8 + hh * 4 + 3] - mean) * rs * wv.w + bb.w;
      orow[i4] = o;
    }
  }
}

extern "C" void kernel_launch(void* const* d_in, const int* in_sizes, int n_in,
                              void* d_out, int out_size, void* d_ws, size_t ws_size,
                              hipStream_t stream) {
  const float* x   = (const float*)d_in[0];
  const float* msk = (const float*)d_in[1];
  const float* Wq  = (const float*)d_in[2];
  const float* bq  = (const float*)d_in[3];
  const float* Wk  = (const float*)d_in[4];
  const float* bk  = (const float*)d_in[5];
  const float* Wv  = (const float*)d_in[6];
  const float* bv  = (const float*)d_in[7];
  const float* Wd  = (const float*)d_in[8];
  const float* bd  = (const float*)d_in[9];
  const float* lnw = (const float*)d_in[10];
  const float* lnb = (const float*)d_in[11];
  float* out = (float*)d_out;

  // workspace layout (bf16 elems), 256 MiB total:
  unsigned short* xb    = (unsigned short*)d_ws;            // 16M
  unsigned short* wqkvb = xb + (size_t)16777216;            // 48M
  unsigned short* wdb   = wqkvb + (size_t)50331648;         // 16M
  unsigned short* qkvb  = wdb + (size_t)16777216;           // 48M
  unsigned short* ctxb  = wqkvb;  // alias: W_qkv dead after GEMM1
  unsigned short* projb = qkvb;   // alias: q/k/v dead after attn (xb stays!)

  // fused conversions: 5 tensors x 2M 8-elem items
  conv_all<<<40960, 256, 0, stream>>>(x, Wq, Wk, Wv, Wd, xb);

  (void)hipFuncSetAttribute((const void*)(gemm_4p<2>),
                            hipFuncAttributeMaxDynamicSharedMemorySize, 131072);
  (void)hipFuncSetAttribute((const void*)(gemm_4p<1>),
                            hipFuncAttributeMaxDynamicSharedMemorySize, 131072);

  // QKV: [4096,12288] = xb[4096,4096] * Wqkv[12288,4096]^T + b  (nwg=768)
  gemm_4p<2><<<768, 512, 131072, stream>>>(xb, wqkvb, bq, bk, bv, qkvb,
                                           4096, 12288, 4096);

  // attention: 512 heads
  (void)hipFuncSetAttribute((const void*)attn_kernel,
                            hipFuncAttributeMaxDynamicSharedMemorySize, 149504);
  attn_kernel<<<512, 512, 149504, stream>>>(qkvb, msk, ctxb);

  // proj (bf16): projb = ctx[4096,4096] * Wd[4096,4096]^T + bd  (nwg=256)
  gemm_4p<1><<<256, 512, 131072, stream>>>(ctxb, wdb, bd, nullptr, nullptr,
                                           projb, 4096, 4096, 4096);

  // residual + LN: out = LN(xb + projb)  (both bf16)
  ln_kernel<<<4096, 256, 0, stream>>>(xb, projb, out, lnw, lnb);
}